// Round 1
// baseline (8691.482 us; speedup 1.0000x reference)
//
#include <hip/hip_runtime.h>
#include <hip/hip_bf16.h>

// Model dims (compile-time constants)
#define TT 2048
#define DD 1024
#define NH 16
#define HS 64
#define FFD 4096
#define VV 32000
#define NL 2
#define TD (TT*DD)   // 2,097,152 floats

// ---------------------------------------------------------------------------
// Embedding: x[t][d] = tok_emb[idx[t]][d] + pos_emb[t][d]
// ---------------------------------------------------------------------------
__global__ __launch_bounds__(256) void embed_kernel(
    const int* __restrict__ idx, const float* __restrict__ tok,
    const float* __restrict__ pos, float* __restrict__ x)
{
    int t = blockIdx.x;
    int d4 = threadIdx.x * 4;
    int token = idx[t];
    float4 a = *(const float4*)&tok[(size_t)token * DD + d4];
    float4 p = *(const float4*)&pos[(size_t)t * DD + d4];
    float4 r;
    r.x = a.x + p.x; r.y = a.y + p.y; r.z = a.z + p.z; r.w = a.w + p.w;
    *(float4*)&x[(size_t)t * DD + d4] = r;
}

// ---------------------------------------------------------------------------
// LayerNorm: out[t][d] = (x - mean) * rsqrt(var + eps) * g + b
// one block (256 threads) per row; D = 1024 -> 4 elems/thread
// ---------------------------------------------------------------------------
__global__ __launch_bounds__(256) void ln_kernel(
    const float* __restrict__ x, const float* __restrict__ g,
    const float* __restrict__ b, float* __restrict__ out)
{
    int t = blockIdx.x;
    int tid = threadIdx.x;
    int d4 = tid * 4;
    float4 xv = *(const float4*)&x[(size_t)t * DD + d4];
    float s  = xv.x + xv.y + xv.z + xv.w;
    float s2 = xv.x*xv.x + xv.y*xv.y + xv.z*xv.z + xv.w*xv.w;
    // wave reduce (64 lanes)
    #pragma unroll
    for (int off = 32; off >= 1; off >>= 1) {
        s  += __shfl_xor(s,  off);
        s2 += __shfl_xor(s2, off);
    }
    __shared__ float ls[4], ls2[4];
    int w = tid >> 6;
    if ((tid & 63) == 0) { ls[w] = s; ls2[w] = s2; }
    __syncthreads();
    float sum  = ls[0] + ls[1] + ls[2] + ls[3];
    float sum2 = ls2[0] + ls2[1] + ls2[2] + ls2[3];
    float mean = sum * (1.0f / DD);
    float var  = sum2 * (1.0f / DD) - mean * mean;
    float r = rsqrtf(var + 1e-5f);
    float4 gv = *(const float4*)&g[d4];
    float4 bv = *(const float4*)&b[d4];
    float4 o;
    o.x = (xv.x - mean) * r * gv.x + bv.x;
    o.y = (xv.y - mean) * r * gv.y + bv.y;
    o.z = (xv.z - mean) * r * gv.z + bv.z;
    o.w = (xv.w - mean) * r * gv.w + bv.w;
    *(float4*)&out[(size_t)t * DD + d4] = o;
}

// ---------------------------------------------------------------------------
// fp32 GEMM: C = A[M,K] * B[K,N] (+bias, epilogue variants)
// BMODE 0: B row-major [K,N]
// BMODE 1: B head-strided: B[c][n] = Bp[(n/64)*K*64 + c*64 + (n%64)]  (wq/wk/wv)
// EPI 0: write to [H][M][64] layout (q/k/v), no bias
// EPI 1: C[row*N+col] = relu(acc + bias[col])
// EPI 2: C[row*N+col] += acc + bias[col]   (residual)
// EPI 3: C[row*N+col] = acc + bias[col]
// tile 64x64, BK=16, 256 threads, 4x4 per thread. M,N,K divide tiles exactly.
// ---------------------------------------------------------------------------
template<int BMODE, int EPI>
__global__ __launch_bounds__(256) void gemm_kernel(
    const float* __restrict__ A, const float* __restrict__ B,
    const float* __restrict__ bias, float* __restrict__ C,
    int M, int N, int K)
{
    __shared__ float As[16][64];
    __shared__ float Bs[16][64];
    int tid = threadIdx.x;
    int bm = blockIdx.y * 64;
    int bn = blockIdx.x * 64;
    int tx = tid & 15, ty = tid >> 4;
    int arow = tid >> 2;            // 0..63
    int ak   = (tid & 3) * 4;       // 0,4,8,12
    int bk   = tid >> 4;            // 0..15
    int bn4  = (tid & 15) * 4;      // 0..60

    float acc[4][4] = {};
    for (int k0 = 0; k0 < K; k0 += 16) {
        float4 av = *(const float4*)&A[(size_t)(bm + arow) * K + k0 + ak];
        As[ak + 0][arow] = av.x;
        As[ak + 1][arow] = av.y;
        As[ak + 2][arow] = av.z;
        As[ak + 3][arow] = av.w;
        float4 bv;
        if (BMODE == 0) {
            bv = *(const float4*)&B[(size_t)(k0 + bk) * N + bn + bn4];
        } else {
            int head = bn >> 6;         // bn multiple of 64, bn4 < 64
            bv = *(const float4*)&B[((size_t)head * K + k0 + bk) * 64 + bn4];
        }
        *(float4*)&Bs[bk][bn4] = bv;
        __syncthreads();
        #pragma unroll
        for (int kk = 0; kk < 16; ++kk) {
            float4 a = *(const float4*)&As[kk][ty * 4];
            float4 bq = *(const float4*)&Bs[kk][tx * 4];
            float ar[4] = {a.x, a.y, a.z, a.w};
            float br[4] = {bq.x, bq.y, bq.z, bq.w};
            #pragma unroll
            for (int i = 0; i < 4; ++i)
                #pragma unroll
                for (int j = 0; j < 4; ++j)
                    acc[i][j] += ar[i] * br[j];
        }
        __syncthreads();
    }
    #pragma unroll
    for (int i = 0; i < 4; ++i) {
        int row = bm + ty * 4 + i;
        #pragma unroll
        for (int j = 0; j < 4; ++j) {
            int col = bn + tx * 4 + j;
            float v = acc[i][j];
            if (EPI == 0) {
                int head = col >> 6, s = col & 63;
                C[((size_t)head * M + row) * 64 + s] = v;
            } else if (EPI == 1) {
                C[(size_t)row * N + col] = fmaxf(v + bias[col], 0.0f);
            } else if (EPI == 2) {
                C[(size_t)row * N + col] += v + bias[col];
            } else {
                C[(size_t)row * N + col] = v + bias[col];
            }
        }
    }
}

// ---------------------------------------------------------------------------
// Causal attention with online softmax.
// One wave per (head, t). lane = head-dim s (HS = 64 exactly one wave).
// q/k/v layout: [H][T][64].  Writes x[t][h*64+s] += att (fused residual).
// scale = D^-0.5 = 1/32 (reference scales by x.shape[-1]**-0.5).
// ---------------------------------------------------------------------------
__global__ __launch_bounds__(256) void attn_kernel(
    const float* __restrict__ q, const float* __restrict__ k,
    const float* __restrict__ v, float* __restrict__ x)
{
    int gw = blockIdx.x * 4 + (threadIdx.x >> 6);
    int lane = threadIdx.x & 63;
    int h = gw >> 11;          // T = 2048 = 2^11
    int t = gw & (TT - 1);
    const float scale = 0.03125f;  // 1/32
    size_t base = (size_t)h * TT * HS;
    float qv = q[base + (size_t)t * HS + lane] * scale;
    float m = -INFINITY, l = 0.0f, o = 0.0f;
    for (int u = 0; u <= t; ++u) {
        float kv = k[base + (size_t)u * HS + lane];
        float s = qv * kv;
        #pragma unroll
        for (int off = 32; off >= 1; off >>= 1)
            s += __shfl_xor(s, off);
        float mn = fmaxf(m, s);
        float c = __expf(m - mn);     // first iter: exp(-inf) = 0
        float p = __expf(s - mn);
        l = l * c + p;
        o = o * c + p * v[base + (size_t)u * HS + lane];
        m = mn;
    }
    x[(size_t)t * DD + h * HS + lane] += o / l;
}

// ---------------------------------------------------------------------------
extern "C" void kernel_launch(void* const* d_in, const int* in_sizes, int n_in,
                              void* d_out, int out_size, void* d_ws, size_t ws_size,
                              hipStream_t stream)
{
    const int*   idx    = (const int*)  d_in[0];
    const float* tok    = (const float*)d_in[1];
    const float* pos    = (const float*)d_in[2];
    const float* ln1_g  = (const float*)d_in[3];
    const float* ln1_b  = (const float*)d_in[4];
    const float* wq     = (const float*)d_in[5];
    const float* wk     = (const float*)d_in[6];
    const float* wv     = (const float*)d_in[7];
    const float* ln2_g  = (const float*)d_in[8];
    const float* ln2_b  = (const float*)d_in[9];
    const float* w1     = (const float*)d_in[10];
    const float* b1     = (const float*)d_in[11];
    const float* w2     = (const float*)d_in[12];
    const float* b2     = (const float*)d_in[13];
    const float* lnf_g  = (const float*)d_in[14];
    const float* lnf_b  = (const float*)d_in[15];
    const float* w_un   = (const float*)d_in[16];
    const float* b_un   = (const float*)d_in[17];
    float* out = (float*)d_out;

    float* ws = (float*)d_ws;
    float* x  = ws;            // [T][D]
    float* h  = ws + TD;       // [T][D]
    float* q  = ws + 2*TD;     // [H][T][64]
    float* kk = ws + 3*TD;
    float* vv = ws + 4*TD;
    float* h1 = ws + 2*TD;     // [T][FF]  (reuses q/k/v region after attention)

    embed_kernel<<<TT, 256, 0, stream>>>(idx, tok, pos, x);

    for (int l = 0; l < NL; ++l) {
        ln_kernel<<<TT, 256, 0, stream>>>(x, ln1_g + l*DD, ln1_b + l*DD, h);
        dim3 gqkv(DD / 64, TT / 64);
        const float* wql = wq + (size_t)l * NH * DD * HS;
        const float* wkl = wk + (size_t)l * NH * DD * HS;
        const float* wvl = wv + (size_t)l * NH * DD * HS;
        gemm_kernel<1,0><<<gqkv, 256, 0, stream>>>(h, wql, nullptr, q,  TT, DD, DD);
        gemm_kernel<1,0><<<gqkv, 256, 0, stream>>>(h, wkl, nullptr, kk, TT, DD, DD);
        gemm_kernel<1,0><<<gqkv, 256, 0, stream>>>(h, wvl, nullptr, vv, TT, DD, DD);

        attn_kernel<<<NH * TT / 4, 256, 0, stream>>>(q, kk, vv, x);

        ln_kernel<<<TT, 256, 0, stream>>>(x, ln2_g + l*DD, ln2_b + l*DD, h);
        gemm_kernel<0,1><<<dim3(FFD/64, TT/64), 256, 0, stream>>>(
            h, w1 + (size_t)l*DD*FFD, b1 + (size_t)l*FFD, h1, TT, FFD, DD);
        gemm_kernel<0,2><<<dim3(DD/64, TT/64), 256, 0, stream>>>(
            h1, w2 + (size_t)l*FFD*DD, b2 + (size_t)l*DD, x, TT, DD, FFD);
    }

    ln_kernel<<<TT, 256, 0, stream>>>(x, lnf_g, lnf_b, h);
    gemm_kernel<0,3><<<dim3(VV/64, TT/64), 256, 0, stream>>>(
        h, w_un, b_un, out, TT, VV, DD);
}

// Round 2
// 803.577 us; speedup vs baseline: 10.8160x; 10.8160x over previous
//
#include <hip/hip_runtime.h>
#include <hip/hip_bf16.h>

#define TT 2048
#define DD 1024
#define NH 16
#define HSZ 64
#define FFD 4096
#define VV 32000
#define NL 2

typedef __bf16 bf16x8 __attribute__((ext_vector_type(8)));
typedef float f32x4 __attribute__((ext_vector_type(4)));

__device__ __forceinline__ unsigned short f2bf(float f) {
    unsigned int u = __float_as_uint(f);
    return (unsigned short)((u + 0x7FFFu + ((u >> 16) & 1u)) >> 16);
}

// async global->LDS, 16B per lane; lds dst is wave-uniform base + lane*16
#define GLL(gsrc, ldst) \
  __builtin_amdgcn_global_load_lds((const __attribute__((address_space(1))) void*)(gsrc), \
                                   (__attribute__((address_space(3))) void*)(ldst), 16, 0, 0)

// XOR swizzles (involutions: XOR bits are disjoint from their key bits)
#define SWZ64(L)  ((L) ^ ((((L) >> 7) & 3) << 4))   // 64B-row tiles (GEMM As/Bs)
#define SWZ128(L) ((L) ^ ((((L) >> 7) & 7) << 4))   // 128B-row tiles (attn Ks/Vs/Ps)

// ---------------------------------------------------------------------------
__global__ __launch_bounds__(256) void embed_kernel(
    const int* __restrict__ idx, const float* __restrict__ tok,
    const float* __restrict__ pos, float* __restrict__ x)
{
    int t = blockIdx.x;
    int d4 = threadIdx.x * 4;
    int token = idx[t];
    float4 a = *(const float4*)&tok[(size_t)token * DD + d4];
    float4 p = *(const float4*)&pos[(size_t)t * DD + d4];
    float4 r;
    r.x = a.x + p.x; r.y = a.y + p.y; r.z = a.z + p.z; r.w = a.w + p.w;
    *(float4*)&x[(size_t)t * DD + d4] = r;
}

// LayerNorm fp32 -> bf16 out
__global__ __launch_bounds__(256) void ln_kernel(
    const float* __restrict__ x, const float* __restrict__ g,
    const float* __restrict__ b, unsigned short* __restrict__ out)
{
    int t = blockIdx.x;
    int tid = threadIdx.x;
    int d4 = tid * 4;
    float4 xv = *(const float4*)&x[(size_t)t * DD + d4];
    float s  = xv.x + xv.y + xv.z + xv.w;
    float s2 = xv.x*xv.x + xv.y*xv.y + xv.z*xv.z + xv.w*xv.w;
    #pragma unroll
    for (int off = 32; off >= 1; off >>= 1) {
        s  += __shfl_xor(s,  off);
        s2 += __shfl_xor(s2, off);
    }
    __shared__ float ls[4], ls2[4];
    int w = tid >> 6;
    if ((tid & 63) == 0) { ls[w] = s; ls2[w] = s2; }
    __syncthreads();
    float sum  = ls[0] + ls[1] + ls[2] + ls[3];
    float sum2 = ls2[0] + ls2[1] + ls2[2] + ls2[3];
    float mean = sum * (1.0f / DD);
    float var  = sum2 * (1.0f / DD) - mean * mean;
    float r = rsqrtf(var + 1e-5f);
    float4 gv = *(const float4*)&g[d4];
    float4 bv = *(const float4*)&b[d4];
    ushort4 pk;
    pk.x = f2bf((xv.x - mean) * r * gv.x + bv.x);
    pk.y = f2bf((xv.y - mean) * r * gv.y + bv.y);
    pk.z = f2bf((xv.z - mean) * r * gv.z + bv.z);
    pk.w = f2bf((xv.w - mean) * r * gv.w + bv.w);
    *(ushort4*)&out[(size_t)t * DD + d4] = pk;
}

// generic cast+transpose: src [R][C] f32 -> dst [C][R] bf16
__global__ __launch_bounds__(256) void tcast(
    const float* __restrict__ src, unsigned short* __restrict__ dst,
    int R, int C, size_t sstride, size_t dstride)
{
    __shared__ float tile[64][65];
    const float* s = src + (size_t)blockIdx.z * sstride;
    unsigned short* d = dst + (size_t)blockIdx.z * dstride;
    int c0 = blockIdx.x * 64, r0 = blockIdx.y * 64;
    #pragma unroll
    for (int i = 0; i < 16; ++i) {
        int id = i * 256 + threadIdx.x;
        int rr = id >> 6, cc = id & 63;
        tile[rr][cc] = s[(size_t)(r0 + rr) * C + (c0 + cc)];
    }
    __syncthreads();
    #pragma unroll
    for (int i = 0; i < 16; ++i) {
        int id = i * 256 + threadIdx.x;
        int cc = id >> 6, rr = id & 63;
        d[(size_t)(c0 + cc) * R + (r0 + rr)] = f2bf(tile[rr][cc]);
    }
}

// wq/wk/wv [L][H][D][HS] f32 -> wqkvT [L][3072][1024] bf16 (row n = mat*1024+h*64+s, col c)
__global__ __launch_bounds__(256) void qkv_tcast(
    const float* __restrict__ wq, const float* __restrict__ wk,
    const float* __restrict__ wv, unsigned short* __restrict__ dst)
{
    __shared__ float tile[64][65];
    int l = blockIdx.z;
    int mat = blockIdx.y >> 4, hh = blockIdx.y & 15;
    const float* s = (mat == 0) ? wq : (mat == 1) ? wk : wv;
    s += (((size_t)l * NH + hh) * DD) * HSZ;   // [1024][64]
    int r0 = blockIdx.x * 64;
    #pragma unroll
    for (int i = 0; i < 16; ++i) {
        int id = i * 256 + threadIdx.x;
        int rr = id >> 6, cc = id & 63;
        tile[rr][cc] = s[(size_t)(r0 + rr) * HSZ + cc];
    }
    __syncthreads();
    unsigned short* d = dst + (size_t)l * 3072 * DD + ((size_t)mat * DD + hh * HSZ) * DD;
    #pragma unroll
    for (int i = 0; i < 16; ++i) {
        int id = i * 256 + threadIdx.x;
        int cc = id >> 6, rr = id & 63;
        d[(size_t)cc * DD + (r0 + rr)] = f2bf(tile[rr][cc]);
    }
}

// ---------------------------------------------------------------------------
// bf16 MFMA GEMM: C = A[M,K] * Bt[N,K]^T, 128x128 tile, BK=32, 4 waves.
// EPI 0: QKV split (outp = qg base; kg/vt contiguous after). no bias.
// EPI 1: bf16 relu(acc+bias) -> [M][FFD]
// EPI 2: fp32 outp[row*DD+col] += acc + bias
// EPI 3: fp32 outp[row*VV+col]  = acc + bias
// ---------------------------------------------------------------------------
template<int EPI>
__global__ __launch_bounds__(256) void mgemm(
    const unsigned short* __restrict__ A, const unsigned short* __restrict__ Bt,
    const float* __restrict__ bias, void* __restrict__ outp,
    int M, int N, int K)
{
    __shared__ unsigned short As[128 * 32];
    __shared__ unsigned short Bs[128 * 32];
    int tid = threadIdx.x;
    int w = tid >> 6, lane = tid & 63;
    int l15 = lane & 15, l4 = lane >> 4;
    int bm = blockIdx.y * 128, bn = blockIdx.x * 128;
    int wr = (w >> 1) * 64, wc = (w & 1) * 64;

    f32x4 zz = {0.f, 0.f, 0.f, 0.f};
    f32x4 acc[4][4];
    #pragma unroll
    for (int m = 0; m < 4; ++m)
        #pragma unroll
        for (int n = 0; n < 4; ++n) acc[m][n] = zz;

    // staging: thread deposits 16B at phys = r*4096 + w*1024 + lane*16
    int t16 = tid * 16;
    int lg = SWZ64(t16);
    int srow = lg >> 6;            // 0..63
    int skel = (lg & 63) >> 1;     // k element offset, multiple of 8
    const unsigned short* aSrc0 = A + (size_t)(bm + srow) * K + skel;
    const unsigned short* aSrc1 = A + (size_t)(bm + 64 + srow) * K + skel;
    const unsigned short* bSrc0 = Bt + (size_t)(bn + srow) * K + skel;
    const unsigned short* bSrc1 = Bt + (size_t)(bn + 64 + srow) * K + skel;
    char* aDst = (char*)As + w * 1024;
    char* bDst = (char*)Bs + w * 1024;

    int aoff[4], boff[4];
    #pragma unroll
    for (int m = 0; m < 4; ++m) {
        int la = (wr + m * 16 + l15) * 64 + l4 * 16;
        aoff[m] = SWZ64(la);
        int lb = (wc + m * 16 + l15) * 64 + l4 * 16;
        boff[m] = SWZ64(lb);
    }

    for (int k0 = 0; k0 < K; k0 += 32) {
        __syncthreads();
        GLL(aSrc0 + k0, aDst);
        GLL(aSrc1 + k0, aDst + 4096);
        GLL(bSrc0 + k0, bDst);
        GLL(bSrc1 + k0, bDst + 4096);
        __syncthreads();
        bf16x8 af[4], bf[4];
        #pragma unroll
        for (int m = 0; m < 4; ++m) af[m] = *(const bf16x8*)((const char*)As + aoff[m]);
        #pragma unroll
        for (int n = 0; n < 4; ++n) bf[n] = *(const bf16x8*)((const char*)Bs + boff[n]);
        #pragma unroll
        for (int m = 0; m < 4; ++m)
            #pragma unroll
            for (int n = 0; n < 4; ++n)
                acc[m][n] = __builtin_amdgcn_mfma_f32_16x16x32_bf16(af[m], bf[n], acc[m][n], 0, 0, 0);
    }

    #pragma unroll
    for (int m = 0; m < 4; ++m) {
        int row0 = bm + wr + m * 16 + l4 * 4;
        #pragma unroll
        for (int n = 0; n < 4; ++n) {
            int col = bn + wc + n * 16 + l15;
            f32x4 v = acc[m][n];
            if (EPI == 0) {
                int mat = col >> 10, hh = (col >> 6) & 15, ss = col & 63;
                unsigned short* base = (unsigned short*)outp + (size_t)mat * ((size_t)NH * TT * HSZ);
                if (mat < 2) {
                    #pragma unroll
                    for (int i = 0; i < 4; ++i)
                        base[((size_t)hh * TT + row0 + i) * HSZ + ss] = f2bf(v[i]);
                } else {
                    ushort4 pk;
                    pk.x = f2bf(v[0]); pk.y = f2bf(v[1]); pk.z = f2bf(v[2]); pk.w = f2bf(v[3]);
                    *(ushort4*)&base[((size_t)hh * HSZ + ss) * TT + row0] = pk;
                }
            } else if (EPI == 1) {
                float bb = bias[col];
                unsigned short* o = (unsigned short*)outp;
                #pragma unroll
                for (int i = 0; i < 4; ++i)
                    o[(size_t)(row0 + i) * FFD + col] = f2bf(fmaxf(v[i] + bb, 0.f));
            } else if (EPI == 2) {
                float bb = bias[col];
                float* xx = (float*)outp;
                #pragma unroll
                for (int i = 0; i < 4; ++i)
                    xx[(size_t)(row0 + i) * DD + col] += v[i] + bb;
            } else {
                float bb = bias[col];
                float* o = (float*)outp;
                #pragma unroll
                for (int i = 0; i < 4; ++i)
                    o[(size_t)(row0 + i) * VV + col] = v[i] + bb;
            }
        }
    }
}

// ---------------------------------------------------------------------------
// Flash attention: block = (head, 64 q rows), 4 waves x 16 rows, KV tiles of 64.
// qg/kg [H][T][64] bf16, vt [H][64][T] bf16. x += softmax(QK^T * D^-0.5) V.
// ---------------------------------------------------------------------------
__global__ __launch_bounds__(256) void attn_kernel(
    const unsigned short* __restrict__ qg, const unsigned short* __restrict__ kg,
    const unsigned short* __restrict__ vt, float* __restrict__ x)
{
    __shared__ unsigned short Ks[64 * 64];      // [u][s] swizzled
    __shared__ unsigned short Vs[64 * 64];      // [s][u] swizzled
    __shared__ unsigned short Ps[4][16 * 64];   // per wave [q][u] swizzled
    int tid = threadIdx.x;
    int w = tid >> 6, lane = tid & 63;
    int l15 = lane & 15, l4 = lane >> 4;
    int hh = blockIdx.y;
    int qb = blockIdx.x * 64;

    const unsigned short* qrow = qg + ((size_t)hh * TT + qb + w * 16 + l15) * HSZ + l4 * 8;
    bf16x8 qf0 = *(const bf16x8*)(qrow);
    bf16x8 qf1 = *(const bf16x8*)(qrow + 32);

    int t16 = tid * 16;
    int lgs = SWZ128(t16);
    int surow = lgs >> 7;          // 0..31
    int subyte = lgs & 127;
    const char* kbase = (const char*)(kg + (size_t)hh * TT * HSZ);
    const char* vbase = (const char*)(vt + (size_t)hh * HSZ * TT);

    f32x4 zz = {0.f, 0.f, 0.f, 0.f};
    f32x4 o[4];
    float mrun[4], lrun[4];
    #pragma unroll
    for (int i = 0; i < 4; ++i) { o[i] = zz; mrun[i] = -INFINITY; lrun[i] = 0.f; }

    const float scale = 0.03125f;  // D^-0.5
    int nkv = (qb >> 6) + 1;
    for (int ib = 0; ib < nkv; ++ib) {
        int ub = ib * 64;
        bool diag = (ub == qb);
        __syncthreads();
        GLL(kbase + (size_t)(ub + surow) * 128 + subyte,        (char*)Ks + w * 1024);
        GLL(kbase + (size_t)(ub + 32 + surow) * 128 + subyte,   (char*)Ks + 4096 + w * 1024);
        GLL(vbase + (size_t)surow * 4096 + ub * 2 + subyte,     (char*)Vs + w * 1024);
        GLL(vbase + (size_t)(surow + 32) * 4096 + ub * 2 + subyte, (char*)Vs + 4096 + w * 1024);
        __syncthreads();

        // S = Q K^T
        f32x4 sfr[4];
        #pragma unroll
        for (int f = 0; f < 4; ++f) {
            int lgb = (f * 16 + l15) * 128 + l4 * 16;
            bf16x8 b0 = *(const bf16x8*)((const char*)Ks + SWZ128(lgb));
            bf16x8 b1 = *(const bf16x8*)((const char*)Ks + SWZ128(lgb + 64));
            f32x4 z = zz;
            z = __builtin_amdgcn_mfma_f32_16x16x32_bf16(qf0, b0, z, 0, 0, 0);
            z = __builtin_amdgcn_mfma_f32_16x16x32_bf16(qf1, b1, z, 0, 0, 0);
            sfr[f] = z;
        }
        // scale + causal mask
        #pragma unroll
        for (int f = 0; f < 4; ++f)
            #pragma unroll
            for (int i = 0; i < 4; ++i) {
                float s = sfr[f][i] * scale;
                if (diag && (f * 16 + l15) > (w * 16 + l4 * 4 + i)) s = -INFINITY;
                sfr[f][i] = s;
            }
        // online softmax (row = q, reduce across 16 lanes + 4 frags)
        #pragma unroll
        for (int i = 0; i < 4; ++i) {
            float t = fmaxf(fmaxf(sfr[0][i], sfr[1][i]), fmaxf(sfr[2][i], sfr[3][i]));
            t = fmaxf(t, __shfl_xor(t, 1));
            t = fmaxf(t, __shfl_xor(t, 2));
            t = fmaxf(t, __shfl_xor(t, 4));
            t = fmaxf(t, __shfl_xor(t, 8));
            float mn = fmaxf(mrun[i], t);
            float c = __expf(mrun[i] - mn);
            mrun[i] = mn;
            float ps = 0.f;
            #pragma unroll
            for (int f = 0; f < 4; ++f) {
                float p = __expf(sfr[f][i] - mn);
                sfr[f][i] = p;
                ps += p;
            }
            ps += __shfl_xor(ps, 1); ps += __shfl_xor(ps, 2);
            ps += __shfl_xor(ps, 4); ps += __shfl_xor(ps, 8);
            lrun[i] = lrun[i] * c + ps;
            #pragma unroll
            for (int sf = 0; sf < 4; ++sf) o[sf][i] *= c;
        }
        // write P (bf16) to wave-private swizzled LDS
        unsigned short* pw = Ps[w];
        #pragma unroll
        for (int i = 0; i < 4; ++i) {
            int q = l4 * 4 + i;
            #pragma unroll
            for (int f = 0; f < 4; ++f) {
                int lgb = q * 128 + (f * 16 + l15) * 2;
                *(unsigned short*)((char*)pw + SWZ128(lgb)) = f2bf(sfr[f][i]);
            }
        }
        // O += P V
        bf16x8 pa0 = *(const bf16x8*)((const char*)pw + SWZ128(l15 * 128 + l4 * 16));
        bf16x8 pa1 = *(const bf16x8*)((const char*)pw + SWZ128(l15 * 128 + 64 + l4 * 16));
        #pragma unroll
        for (int sf = 0; sf < 4; ++sf) {
            int lgb = (sf * 16 + l15) * 128 + l4 * 16;
            bf16x8 v0 = *(const bf16x8*)((const char*)Vs + SWZ128(lgb));
            bf16x8 v1 = *(const bf16x8*)((const char*)Vs + SWZ128(lgb + 64));
            o[sf] = __builtin_amdgcn_mfma_f32_16x16x32_bf16(pa0, v0, o[sf], 0, 0, 0);
            o[sf] = __builtin_amdgcn_mfma_f32_16x16x32_bf16(pa1, v1, o[sf], 0, 0, 0);
        }
    }
    float rl[4];
    #pragma unroll
    for (int i = 0; i < 4; ++i) rl[i] = 1.0f / lrun[i];
    #pragma unroll
    for (int sf = 0; sf < 4; ++sf)
        #pragma unroll
        for (int i = 0; i < 4; ++i) {
            int q = qb + w * 16 + l4 * 4 + i;
            int d = hh * HSZ + sf * 16 + l15;
            x[(size_t)q * DD + d] += o[sf][i] * rl[i];
        }
}

// ---------------------------------------------------------------------------
extern "C" void kernel_launch(void* const* d_in, const int* in_sizes, int n_in,
                              void* d_out, int out_size, void* d_ws, size_t ws_size,
                              hipStream_t stream)
{
    const int*   idx    = (const int*)  d_in[0];
    const float* tok    = (const float*)d_in[1];
    const float* pos    = (const float*)d_in[2];
    const float* ln1_g  = (const float*)d_in[3];
    const float* ln1_b  = (const float*)d_in[4];
    const float* wq     = (const float*)d_in[5];
    const float* wk     = (const float*)d_in[6];
    const float* wv     = (const float*)d_in[7];
    const float* ln2_g  = (const float*)d_in[8];
    const float* ln2_b  = (const float*)d_in[9];
    const float* w1     = (const float*)d_in[10];
    const float* b1     = (const float*)d_in[11];
    const float* w2     = (const float*)d_in[12];
    const float* b2     = (const float*)d_in[13];
    const float* lnf_g  = (const float*)d_in[14];
    const float* lnf_b  = (const float*)d_in[15];
    const float* w_un   = (const float*)d_in[16];
    const float* b_un   = (const float*)d_in[17];
    float* out = (float*)d_out;

    char* W = (char*)d_ws;
    float*          x    = (float*)(W);                          // 8 MB
    unsigned short* h    = (unsigned short*)(W + 8388608);       // 4 MB
    unsigned short* qg   = (unsigned short*)(W + 12582912);      // 4 MB
    unsigned short* kg   = (unsigned short*)(W + 16777216);      // 4 MB  (qg+2M shorts)
    unsigned short* vt   = (unsigned short*)(W + 20971520);      // 4 MB
    unsigned short* h1   = (unsigned short*)(W + 25165824);      // 16 MB
    unsigned short* wqkvT= (unsigned short*)(W + 41943040);      // 12.6 MB
    unsigned short* w1T  = (unsigned short*)(W + 54525952);      // 16.8 MB
    unsigned short* w2T  = (unsigned short*)(W + 71303168);      // 16.8 MB
    unsigned short* wunT = (unsigned short*)(W + 88080384);      // 65.5 MB -> 153.6 MB total
    (void)kg; (void)ws_size; (void)in_sizes; (void)n_in; (void)out_size;

    // weight conversion (per call; ~330 MB traffic)
    qkv_tcast<<<dim3(16, 48, 2), 256, 0, stream>>>(wq, wk, wv, wqkvT);
    tcast<<<dim3(64, 16, 2), 256, 0, stream>>>(w1, w1T, DD, FFD, (size_t)DD * FFD, (size_t)DD * FFD);
    tcast<<<dim3(16, 64, 2), 256, 0, stream>>>(w2, w2T, FFD, DD, (size_t)FFD * DD, (size_t)FFD * DD);
    tcast<<<dim3(500, 16, 1), 256, 0, stream>>>(w_un, wunT, DD, VV, 0, 0);

    embed_kernel<<<TT, 256, 0, stream>>>(idx, tok, pos, x);

    for (int l = 0; l < NL; ++l) {
        ln_kernel<<<TT, 256, 0, stream>>>(x, ln1_g + l * DD, ln1_b + l * DD, h);
        mgemm<0><<<dim3(24, 16), 256, 0, stream>>>(h, wqkvT + (size_t)l * 3072 * DD, nullptr, qg, TT, 3072, DD);
        attn_kernel<<<dim3(32, 16), 256, 0, stream>>>(qg, kg, vt, x);
        ln_kernel<<<TT, 256, 0, stream>>>(x, ln2_g + l * DD, ln2_b + l * DD, h);
        mgemm<1><<<dim3(32, 16), 256, 0, stream>>>(h, w1T + (size_t)l * FFD * DD, b1 + (size_t)l * FFD, h1, TT, FFD, DD);
        mgemm<2><<<dim3(8, 16), 256, 0, stream>>>(h1, w2T + (size_t)l * DD * FFD, b2 + (size_t)l * DD, x, TT, DD, FFD);
    }

    ln_kernel<<<TT, 256, 0, stream>>>(x, lnf_g, lnf_b, h);
    mgemm<3><<<dim3(250, 16), 256, 0, stream>>>(h, wunT, b_un, out, TT, VV, DD);
}